// Round 1
// baseline (864.244 us; speedup 1.0000x reference)
//
#include <hip/hip_runtime.h>
#include <hip/hip_bf16.h>

// ---------------- problem constants ----------------
#define BB   2
#define TT   8
#define YY   128
#define XX   128
#define CINv 128
#define COUTv 64
#define YOv  255
#define XOv  255
#define NVOX 262144
#define NSITES (BB*TT*YY*XX)                 // 262,144 input sites
#define CAP  16
#define OUT_SITES (BB*TT*YOv*XOv)            // 1,040,400
#define OUT_ELEMS ((size_t)OUT_SITES*COUTv)  // 66,585,600

typedef float  f32x4  __attribute__((ext_vector_type(4)));
typedef __bf16 bf16x8 __attribute__((ext_vector_type(8)));
typedef unsigned int u32x4 __attribute__((ext_vector_type(4)));

union FragU { u32x4 u; bf16x8 b; };
union Pack8 { unsigned short s[8]; u32x4 u; };

// ---------------- workspace layout (bytes) ----------------
constexpr size_t OFF_STATS = 0;                          // gsum[64]@0, gsq[64]@256, ncnt@512
constexpr size_t OFF_CNT   = 1024;                       // 262144*4 = 1,048,576
constexpr size_t ZERO_BYTES= OFF_CNT + 1048576;          // 1,049,600
constexpr size_t OFF_DBF   = ZERO_BYTES;                 // 262144*128*2 = 67,108,864
constexpr size_t OFF_PB    = OFF_DBF + 67108864;         // 27*16*64*8*2 = 442,368
constexpr size_t OFF_MASK  = OFF_PB + 442368;            // 1,040,400 (pad 1 MiB)
constexpr size_t OFF_SS    = OFF_MASK + 1048576;         // scale[64], shift[64]
// idx (used only by k_count/k_gather) aliases outb (used only by k_conv/k_norm)
constexpr size_t OFF_IDX   = OFF_SS + 1024;              // 262144*16*4 = 16,777,216
constexpr size_t OFF_OUTB  = OFF_IDX;                    // OUT_ELEMS*2 = 133,171,200
// total ~193.4 MiB

__device__ __forceinline__ unsigned short f2bf(float f) {
    unsigned u = __float_as_uint(f);
    u += 0x7fffu + ((u >> 16) & 1u);       // round-to-nearest-even
    return (unsigned short)(u >> 16);
}

__device__ __forceinline__ void gld16(const void* g, void* l) {
    __builtin_amdgcn_global_load_lds(
        (const __attribute__((address_space(1))) unsigned int*)g,
        (__attribute__((address_space(3))) unsigned int*)l, 16, 0, 0);
}

// ---------------- pass 1: per-site voxel lists ----------------
__global__ __launch_bounds__(256) void k_count(
    const int* __restrict__ cb, const int* __restrict__ ct,
    const int* __restrict__ cy, const int* __restrict__ cx,
    unsigned int* __restrict__ cnt, int* __restrict__ idx)
{
    int n = blockIdx.x * 256 + threadIdx.x;     // NVOX threads
    int site = ((cb[n] * TT + ct[n]) * YY + cy[n]) * XX + cx[n];
    unsigned slot = atomicAdd(cnt + site, 1u);
    if (slot < CAP) idx[site * CAP + slot] = n;  // P(overflow) ~ 4e-9 for Poisson(1)
}

// ---------------- pass 2: gather-sum feats -> bf16 dense grid ----------------
__global__ __launch_bounds__(256) void k_gather(
    const float* __restrict__ feats,
    const unsigned int* __restrict__ cnt, const int* __restrict__ idx,
    unsigned short* __restrict__ Dbf)
{
    int tid = blockIdx.x * 256 + threadIdx.x;   // NSITES*16 threads
    int site = tid >> 4;
    int c8 = (tid & 15) * 8;
    unsigned c = cnt[site]; if (c > CAP) c = CAP;
    float a[8] = {0.f,0.f,0.f,0.f,0.f,0.f,0.f,0.f};
    const int* ip = idx + (size_t)site * CAP;
    for (unsigned v = 0; v < c; ++v) {
        int n = ip[v];
        const float4 f0 = *(const float4*)(feats + (size_t)n * CINv + c8);
        const float4 f1 = *(const float4*)(feats + (size_t)n * CINv + c8 + 4);
        a[0] += f0.x; a[1] += f0.y; a[2] += f0.z; a[3] += f0.w;
        a[4] += f1.x; a[5] += f1.y; a[6] += f1.z; a[7] += f1.w;
    }
    Pack8 p;
    #pragma unroll
    for (int j = 0; j < 8; ++j) p.s[j] = f2bf(a[j]);
    *(u32x4*)(Dbf + (size_t)site * CINv + c8) = p.u;
}

// ---------------- pass 3: pack weights into MFMA B-fragments ----------------
// PB layout: [w(27)][f(16)=kc*4+nt][lane(64)][8 bf16]  (16 KB per tap tile)
__global__ __launch_bounds__(64) void k_pack(
    const float* __restrict__ W, unsigned short* __restrict__ PB)
{
    int f = blockIdx.x;                 // 0..431 = w*16 + kc*4 + nt
    int w  = f >> 4;
    int kc = (f >> 2) & 3;
    int nt = f & 3;
    int lane = threadIdx.x;
    int q = lane >> 4, col = lane & 15;
    Pack8 p;
    #pragma unroll
    for (int j = 0; j < 8; ++j) {
        int k  = kc * 32 + q * 8 + j;
        int nn = nt * 16 + col;
        p.s[j] = f2bf(W[((size_t)w * CINv + k) * COUTv + nn]);
    }
    *(u32x4*)(PB + ((size_t)f * 64 + lane) * 8) = p.u;
}

// ---------------- pass 4: active-site mask + count ----------------
__global__ __launch_bounds__(256) void k_mask(
    const unsigned int* __restrict__ occ,
    unsigned char* __restrict__ mask, unsigned int* __restrict__ ncnt)
{
    int s = blockIdx.x * 256 + threadIdx.x;
    bool found = false;
    if (s < OUT_SITES) {
        int xo = s % XOv; int r = s / XOv;
        int yo = r % YOv; r /= YOv;
        int to = r & 7;   int b = r >> 3;
        int cts[3]; int ntc = 0;
        for (int kt = 0; kt < 3; ++kt) { int c = to + 1 - kt; if (c >= 0 && c < TT) cts[ntc++] = c; }
        int cys[2]; int nyc;
        if (yo & 1) { cys[0] = (yo + 1) >> 1; cys[1] = (yo - 1) >> 1; nyc = 2; }
        else        { cys[0] = yo >> 1; nyc = 1; }
        int cxs[2]; int nxc;
        if (xo & 1) { cxs[0] = (xo + 1) >> 1; cxs[1] = (xo - 1) >> 1; nxc = 2; }
        else        { cxs[0] = xo >> 1; nxc = 1; }
        for (int i = 0; i < ntc && !found; ++i)
            for (int j = 0; j < nyc && !found; ++j)
                for (int k = 0; k < nxc && !found; ++k)
                    if (occ[((b * TT + cts[i]) * YY + cys[j]) * XX + cxs[k]]) found = true;
        mask[s] = found ? 1 : 0;
    }
    unsigned long long bal = __ballot(found);
    if ((threadIdx.x & 63) == 0) {
        unsigned c = (unsigned)__popcll(bal);
        if (c) atomicAdd(ncnt, c);
    }
}

// ---------------- pass 5: MFMA transpose-conv, LDS-staged B ----------------
// Block = one output row (b,to,yo), 4 waves. Wave w handles 4 x-chunks:
// (cb8=2w,px=0),(2w,1),(2w+1,0),(2w+1,1). Per (kt,ky): stage 3 kx tiles
// (48 KB) into LDS once; A0 (cxoff=0) loads issued BEFORE the staging
// barrier so the vmcnt(0) drain covers their latency. kx=1 and kx=2 share
// A0 (identical fragments — dedup saves 8 of 24 global loads per round);
// kx=0 needs A1 (cxoff=1), loaded into the same registers after kx=2.
// XCD swizzle: 4080 rows = 8*510 exactly -> bijective chunked remap so
// each XCD's L2 sees a contiguous yo-range of Dbf planes.

#define BPASS(bt, A_a, A_b, SLOT) do {                                                   \
    _Pragma("unroll")                                                                    \
    for (int kc = 0; kc < 4; ++kc) {                                                     \
        FragU Bf[4];                                                                     \
        _Pragma("unroll")                                                                \
        for (int nt = 0; nt < 4; ++nt)                                                   \
            Bf[nt].u = *(const u32x4*)((bt) + (size_t)((kc * 4 + nt) * 64 + lane) * 8);  \
        _Pragma("unroll")                                                                \
        for (int nt = 0; nt < 4; ++nt) {                                                 \
            acc[SLOT][nt]     = __builtin_amdgcn_mfma_f32_16x16x32_bf16(                 \
                                    A_a[kc].b, Bf[nt].b, acc[SLOT][nt], 0, 0, 0);        \
            acc[SLOT + 2][nt] = __builtin_amdgcn_mfma_f32_16x16x32_bf16(                 \
                                    A_b[kc].b, Bf[nt].b, acc[SLOT + 2][nt], 0, 0, 0);    \
        }                                                                                \
    } } while (0)

__global__ __launch_bounds__(256, 3) void k_conv(
    const unsigned short* __restrict__ Dbf,
    const unsigned short* __restrict__ PB,
    unsigned short* __restrict__ outb,
    float* __restrict__ gsum, float* __restrict__ gsq)
{
    const int lane = threadIdx.x & 63;
    const int wave = threadIdx.x >> 6;
    const int bid = blockIdx.x;
    const int row_id = (bid & 7) * 510 + (bid >> 3);   // XCD-chunked, bijective (4080=8*510)
    const int yo = row_id % YOv;
    int r2 = row_id / YOv;
    const int to = r2 & 7;
    const int b  = r2 >> 3;
    const int m = lane & 15, q = lane >> 4;

    __shared__ __align__(16) unsigned short shB[3 * 16 * 64 * 8];   // 48 KB
    __shared__ float shsum[64], shsq[64];
    if (threadIdx.x < 64) { shsum[threadIdx.x] = 0.f; shsq[threadIdx.x] = 0.f; }

    int ycy[2], yky[2], ny;
    if ((yo & 1) == 0) { ny = 1; ycy[0] = yo >> 1; yky[0] = 1; }
    else { ny = 2; ycy[0] = (yo + 1) >> 1; yky[0] = 0; ycy[1] = (yo - 1) >> 1; yky[1] = 2; }

    f32x4 acc[4][4];   // [slot: a-even, a-odd, b-even, b-odd][nt]
    #pragma unroll
    for (int ch = 0; ch < 4; ++ch)
        #pragma unroll
        for (int nt = 0; nt < 4; ++nt) acc[ch][nt] = (f32x4){0.f, 0.f, 0.f, 0.f};

    for (int kt = 0; kt < 3; ++kt) {
        int ct = to + 1 - kt;
        if (ct < 0 || ct >= TT) continue;        // uniform over block
        for (int iy = 0; iy < ny; ++iy) {        // uniform over block
            __syncthreads();                      // protect LDS from prior readers
            {
                const char* gsrc = (const char*)PB + (size_t)((kt * 3 + yky[iy]) * 3) * 16384;
                char* ldst = (char*)shB;
                #pragma unroll
                for (int r = 0; r < 12; ++r)
                    gld16(gsrc + r * 4096 + threadIdx.x * 16,
                          ldst + r * 4096 + wave * 1024);
            }
            // A0 (cxoff=0) loads issued pre-barrier: drained together with staging.
            size_t plane = ((size_t)((b * TT + ct) * YY + ycy[iy])) * XX;
            const unsigned short* Ara0 = Dbf + (plane + (size_t)(2 * wave * 16 + m)) * CINv;
            const unsigned short* Arb0 = Dbf + (plane + (size_t)((2 * wave + 1) * 16 + m)) * CINv;
            FragU Aa[4], Ab[4];
            #pragma unroll
            for (int kc = 0; kc < 4; ++kc) {
                Aa[kc].u = *(const u32x4*)(Ara0 + kc * 32 + q * 8);
                Ab[kc].u = *(const u32x4*)(Arb0 + kc * 32 + q * 8);
            }
            __syncthreads();

            BPASS(shB + 8192,  Aa, Ab, 0);   // kx=1 -> even-parity outputs
            BPASS(shB + 16384, Aa, Ab, 1);   // kx=2 -> odd-parity outputs (same A0)

            // A1 (cxoff=1) into the same registers (only cxb can hit 128 -> clamp)
            {
                int cxb1 = (2 * wave + 1) * 16 + m + 1; if (cxb1 > 127) cxb1 = 127;
                const unsigned short* Ara1 = Dbf + (plane + (size_t)(2 * wave * 16 + m + 1)) * CINv;
                const unsigned short* Arb1 = Dbf + (plane + (size_t)cxb1) * CINv;
                #pragma unroll
                for (int kc = 0; kc < 4; ++kc) {
                    Aa[kc].u = *(const u32x4*)(Ara1 + kc * 32 + q * 8);
                    Ab[kc].u = *(const u32x4*)(Arb1 + kc * 32 + q * 8);
                }
            }
            BPASS(shB + 0, Aa, Ab, 1);       // kx=0 -> odd-parity outputs
        }
    }

    // epilogue: bf16 store + per-channel partial stats
    size_t rowbase = ((size_t)((b * TT + to) * YOv + yo)) * XOv;
    float sl[4] = {0.f,0.f,0.f,0.f}, sq[4] = {0.f,0.f,0.f,0.f};
    #pragma unroll
    for (int ch = 0; ch < 4; ++ch) {
        int cb8 = 2 * wave + (ch >> 1);
        int px = ch & 1;
        #pragma unroll
        for (int nt = 0; nt < 4; ++nt) {
            int c = nt * 16 + m;
            #pragma unroll
            for (int i = 0; i < 4; ++i) {
                int r = q * 4 + i;
                int xo = 2 * (cb8 * 16 + r) + px;
                if (xo < XOv) {
                    float v = acc[ch][nt][i];
                    outb[(rowbase + xo) * COUTv + c] = f2bf(v);
                    sl[nt] += v; sq[nt] += v * v;
                }
            }
        }
    }
    #pragma unroll
    for (int nt = 0; nt < 4; ++nt) {
        sl[nt] += __shfl_xor(sl[nt], 16); sl[nt] += __shfl_xor(sl[nt], 32);
        sq[nt] += __shfl_xor(sq[nt], 16); sq[nt] += __shfl_xor(sq[nt], 32);
    }
    if (lane < 16) {
        #pragma unroll
        for (int nt = 0; nt < 4; ++nt) {
            atomicAdd(&shsum[nt * 16 + lane], sl[nt]);
            atomicAdd(&shsq [nt * 16 + lane], sq[nt]);
        }
    }
    __syncthreads();
    if (threadIdx.x < 64) {
        unsafeAtomicAdd(&gsum[threadIdx.x], shsum[threadIdx.x]);
        unsafeAtomicAdd(&gsq [threadIdx.x], shsq [threadIdx.x]);
    }
}

// ---------------- pass 6: finalize BN stats ----------------
__global__ __launch_bounds__(64) void k_final(
    const float* __restrict__ gsum, const float* __restrict__ gsq,
    const unsigned int* __restrict__ ncnt,
    const float* __restrict__ gamma, const float* __restrict__ beta,
    float* __restrict__ scale, float* __restrict__ shift)
{
    int c = threadIdx.x;
    float nf = (float)max(*ncnt, 1u);
    float mean = gsum[c] / nf;
    float var  = gsq[c] / nf - mean * mean;
    float rstd = rsqrtf(var + 1e-5f);
    float sc = rstd * gamma[c];
    scale[c] = sc;
    shift[c] = beta[c] - mean * sc;
}

// ---------------- pass 7: normalize + mask + relu (bf16 -> fp32) ----------------
__global__ __launch_bounds__(256) void k_norm(
    const unsigned short* __restrict__ outb, float* __restrict__ out,
    const unsigned char* __restrict__ mask,
    const float* __restrict__ scale, const float* __restrict__ shift)
{
    __shared__ float ssc[64], ssh[64];
    if (threadIdx.x < 64) { ssc[threadIdx.x] = scale[threadIdx.x]; ssh[threadIdx.x] = shift[threadIdx.x]; }
    __syncthreads();
    size_t t = (size_t)blockIdx.x * 256 + threadIdx.x;
    size_t e = t * 8;
    if (e >= OUT_ELEMS) return;
    Pack8 p; p.u = *(const u32x4*)(outb + e);
    int c = (int)(e & 63);
    size_t site = e >> 6;
    float4 v0, v1;
    if (mask[site]) {
        float w[8];
        #pragma unroll
        for (int j = 0; j < 8; ++j) {
            float f = __uint_as_float((unsigned)p.s[j] << 16);
            w[j] = fmaxf(fmaf(f, ssc[c + j], ssh[c + j]), 0.f);
        }
        v0 = make_float4(w[0], w[1], w[2], w[3]);
        v1 = make_float4(w[4], w[5], w[6], w[7]);
    } else {
        v0 = make_float4(0.f, 0.f, 0.f, 0.f);
        v1 = v0;
    }
    *(float4*)(out + e) = v0;
    *(float4*)(out + e + 4) = v1;
}

// ---------------- launch ----------------
extern "C" void kernel_launch(void* const* d_in, const int* in_sizes, int n_in,
                              void* d_out, int out_size, void* d_ws, size_t ws_size,
                              hipStream_t stream)
{
    const float* feats = (const float*)d_in[0];
    const float* W     = (const float*)d_in[1];
    const float* gamma = (const float*)d_in[2];
    const float* beta  = (const float*)d_in[3];
    const int* cb = (const int*)d_in[4];
    const int* ct = (const int*)d_in[5];
    const int* cy = (const int*)d_in[6];
    const int* cx = (const int*)d_in[7];
    float* out = (float*)d_out;

    char* ws = (char*)d_ws;
    float*          gsum = (float*)(ws + OFF_STATS);
    float*          gsq  = gsum + 64;
    unsigned int*   ncnt = (unsigned int*)(ws + OFF_STATS + 512);
    unsigned int*   cnt  = (unsigned int*)(ws + OFF_CNT);
    unsigned short* Dbf  = (unsigned short*)(ws + OFF_DBF);
    unsigned short* PB   = (unsigned short*)(ws + OFF_PB);
    unsigned char*  mask = (unsigned char*)(ws + OFF_MASK);
    float*          scale= (float*)(ws + OFF_SS);
    float*          shift= scale + 64;
    int*            idx  = (int*)(ws + OFF_IDX);
    unsigned short* outb = (unsigned short*)(ws + OFF_OUTB);   // aliases idx (ordered)

    hipMemsetAsync(d_ws, 0, ZERO_BYTES, stream);

    k_count<<<NVOX / 256, 256, 0, stream>>>(cb, ct, cy, cx, cnt, idx);
    k_gather<<<NSITES * 16 / 256, 256, 0, stream>>>(feats, cnt, idx, Dbf);
    k_pack<<<27 * 16, 64, 0, stream>>>(W, PB);
    k_mask<<<(OUT_SITES + 255) / 256, 256, 0, stream>>>(cnt, mask, ncnt);
    k_conv<<<BB * TT * YOv, 256, 0, stream>>>(Dbf, PB, outb, gsum, gsq);
    k_final<<<1, 64, 0, stream>>>(gsum, gsq, ncnt, gamma, beta, scale, shift);
    k_norm<<<(int)((OUT_ELEMS / 8 + 255) / 256), 256, 0, stream>>>(outb, out, mask, scale, shift);
}

// Round 2
// 826.480 us; speedup vs baseline: 1.0457x; 1.0457x over previous
//
#include <hip/hip_runtime.h>
#include <hip/hip_bf16.h>

// ---------------- problem constants ----------------
#define BB   2
#define TT   8
#define YY   128
#define XX   128
#define CINv 128
#define COUTv 64
#define YOv  255
#define XOv  255
#define NVOX 262144
#define NSITES (BB*TT*YY*XX)                 // 262,144 input sites
#define CAP  16
#define OUT_SITES (BB*TT*YOv*XOv)            // 1,040,400
#define OUT_ELEMS ((size_t)OUT_SITES*COUTv)  // 66,585,600

typedef float  f32x4  __attribute__((ext_vector_type(4)));
typedef __bf16 bf16x8 __attribute__((ext_vector_type(8)));
typedef unsigned int u32x4 __attribute__((ext_vector_type(4)));

union FragU { u32x4 u; bf16x8 b; };
union Pack8 { unsigned short s[8]; u32x4 u; };

// ---------------- workspace layout (bytes) ----------------
constexpr size_t OFF_STATS = 0;                          // gsum[64]@0, gsq[64]@256, ncnt@512
constexpr size_t OFF_CNT   = 1024;                       // 262144*4 = 1,048,576
constexpr size_t ZERO_BYTES= OFF_CNT + 1048576;          // 1,049,600
constexpr size_t OFF_DBF   = ZERO_BYTES;                 // 262144*128*2 = 67,108,864
constexpr size_t OFF_PB    = OFF_DBF + 67108864;         // 27*16*64*8*2 = 442,368
constexpr size_t OFF_MASK  = OFF_PB + 442368;            // 1,040,400 (pad 1 MiB)
constexpr size_t OFF_SS    = OFF_MASK + 1048576;         // scale[64], shift[64]
// idx (used only by k_count/k_gather) aliases outb (used only by k_conv/k_norm)
constexpr size_t OFF_IDX   = OFF_SS + 1024;              // 262144*16*4 = 16,777,216
constexpr size_t OFF_OUTB  = OFF_IDX;                    // OUT_ELEMS*2 = 133,171,200
// total ~193.4 MiB

__device__ __forceinline__ unsigned short f2bf(float f) {
    unsigned u = __float_as_uint(f);
    u += 0x7fffu + ((u >> 16) & 1u);       // round-to-nearest-even
    return (unsigned short)(u >> 16);
}

__device__ __forceinline__ void gld16(const void* g, void* l) {
    __builtin_amdgcn_global_load_lds(
        (const __attribute__((address_space(1))) unsigned int*)g,
        (__attribute__((address_space(3))) unsigned int*)l, 16, 0, 0);
}

// ---------------- pass 1: per-site voxel lists ----------------
__global__ __launch_bounds__(256) void k_count(
    const int* __restrict__ cb, const int* __restrict__ ct,
    const int* __restrict__ cy, const int* __restrict__ cx,
    unsigned int* __restrict__ cnt, int* __restrict__ idx)
{
    int n = blockIdx.x * 256 + threadIdx.x;     // NVOX threads
    int site = ((cb[n] * TT + ct[n]) * YY + cy[n]) * XX + cx[n];
    unsigned slot = atomicAdd(cnt + site, 1u);
    if (slot < CAP) idx[site * CAP + slot] = n;  // P(overflow) ~ 4e-9 for Poisson(1)
}

// ---------------- pass 2: gather-sum feats -> bf16 dense grid ----------------
__global__ __launch_bounds__(256) void k_gather(
    const float* __restrict__ feats,
    const unsigned int* __restrict__ cnt, const int* __restrict__ idx,
    unsigned short* __restrict__ Dbf)
{
    int tid = blockIdx.x * 256 + threadIdx.x;   // NSITES*16 threads
    int site = tid >> 4;
    int c8 = (tid & 15) * 8;
    unsigned c = cnt[site]; if (c > CAP) c = CAP;
    float a[8] = {0.f,0.f,0.f,0.f,0.f,0.f,0.f,0.f};
    const int* ip = idx + (size_t)site * CAP;
    for (unsigned v = 0; v < c; ++v) {
        int n = ip[v];
        const float4 f0 = *(const float4*)(feats + (size_t)n * CINv + c8);
        const float4 f1 = *(const float4*)(feats + (size_t)n * CINv + c8 + 4);
        a[0] += f0.x; a[1] += f0.y; a[2] += f0.z; a[3] += f0.w;
        a[4] += f1.x; a[5] += f1.y; a[6] += f1.z; a[7] += f1.w;
    }
    Pack8 p;
    #pragma unroll
    for (int j = 0; j < 8; ++j) p.s[j] = f2bf(a[j]);
    *(u32x4*)(Dbf + (size_t)site * CINv + c8) = p.u;
}

// ---------------- pass 3: pack weights into MFMA B-fragments ----------------
// PB layout: [w(27)][f(16)=kc*4+nt][lane(64)][8 bf16]  (16 KB per tap tile)
__global__ __launch_bounds__(64) void k_pack(
    const float* __restrict__ W, unsigned short* __restrict__ PB)
{
    int f = blockIdx.x;                 // 0..431 = w*16 + kc*4 + nt
    int w  = f >> 4;
    int kc = (f >> 2) & 3;
    int nt = f & 3;
    int lane = threadIdx.x;
    int q = lane >> 4, col = lane & 15;
    Pack8 p;
    #pragma unroll
    for (int j = 0; j < 8; ++j) {
        int k  = kc * 32 + q * 8 + j;
        int nn = nt * 16 + col;
        p.s[j] = f2bf(W[((size_t)w * CINv + k) * COUTv + nn]);
    }
    *(u32x4*)(PB + ((size_t)f * 64 + lane) * 8) = p.u;
}

// ---------------- pass 4: active-site mask + count ----------------
__global__ __launch_bounds__(256) void k_mask(
    const unsigned int* __restrict__ occ,
    unsigned char* __restrict__ mask, unsigned int* __restrict__ ncnt)
{
    int s = blockIdx.x * 256 + threadIdx.x;
    bool found = false;
    if (s < OUT_SITES) {
        int xo = s % XOv; int r = s / XOv;
        int yo = r % YOv; r /= YOv;
        int to = r & 7;   int b = r >> 3;
        int cts[3]; int ntc = 0;
        for (int kt = 0; kt < 3; ++kt) { int c = to + 1 - kt; if (c >= 0 && c < TT) cts[ntc++] = c; }
        int cys[2]; int nyc;
        if (yo & 1) { cys[0] = (yo + 1) >> 1; cys[1] = (yo - 1) >> 1; nyc = 2; }
        else        { cys[0] = yo >> 1; nyc = 1; }
        int cxs[2]; int nxc;
        if (xo & 1) { cxs[0] = (xo + 1) >> 1; cxs[1] = (xo - 1) >> 1; nxc = 2; }
        else        { cxs[0] = xo >> 1; nxc = 1; }
        for (int i = 0; i < ntc && !found; ++i)
            for (int j = 0; j < nyc && !found; ++j)
                for (int k = 0; k < nxc && !found; ++k)
                    if (occ[((b * TT + cts[i]) * YY + cys[j]) * XX + cxs[k]]) found = true;
        mask[s] = found ? 1 : 0;
    }
    unsigned long long bal = __ballot(found);
    if ((threadIdx.x & 63) == 0) {
        unsigned c = (unsigned)__popcll(bal);
        if (c) atomicAdd(ncnt, c);
    }
}

// ---------------- pass 5: MFMA transpose-conv, dual-row, LDS-staged B --------
// Block = TWO same-parity output rows (yo0, yo0+2) of one (b,to); 4 waves.
// Same kt/ky schedule for both rows (same parity); planes differ by +1 in cy.
// Per stage (kt,ky): stage 48 KB (3 kx tap tiles) into LDS ONCE, then each
// B fragment read feeds 4 MFMAs (2 x-chunks x 2 rows) -> per-row LDS traffic
// and per-row barrier count both halved vs the single-row version.
// A0 (cxoff=0) for both rows issued pre-barrier (drained with staging);
// kx=1,2 share A0; kx=0 reloads the same regs as A1 (cxoff=1).
// Row pairing per (b,to): g<64 -> even pair (4g, 4g+2); 64<=g<127 -> odd pair
// (4(g-64)+1, +2); g==127 -> singleton yo=253 (row1 clamped+masked).
// Grid 2048 = 8*256 -> bijective XCD-chunked swizzle.

#define MFMA_BF16(A, B, C) __builtin_amdgcn_mfma_f32_16x16x32_bf16((A), (B), (C), 0, 0, 0)

#define BPASS2(bt, SLOT) do {                                                            \
    _Pragma("unroll")                                                                    \
    for (int kc = 0; kc < 4; ++kc) {                                                     \
        FragU Bf[4];                                                                     \
        _Pragma("unroll")                                                                \
        for (int nt = 0; nt < 4; ++nt)                                                   \
            Bf[nt].u = *(const u32x4*)((bt) + (size_t)((kc * 4 + nt) * 64 + lane) * 8);  \
        _Pragma("unroll")                                                                \
        for (int nt = 0; nt < 4; ++nt) {                                                 \
            acc0[SLOT][nt]     = MFMA_BF16(Aa0[kc].b, Bf[nt].b, acc0[SLOT][nt]);         \
            acc0[SLOT + 2][nt] = MFMA_BF16(Ab0[kc].b, Bf[nt].b, acc0[SLOT + 2][nt]);     \
            acc1[SLOT][nt]     = MFMA_BF16(Aa1[kc].b, Bf[nt].b, acc1[SLOT][nt]);         \
            acc1[SLOT + 2][nt] = MFMA_BF16(Ab1[kc].b, Bf[nt].b, acc1[SLOT + 2][nt]);     \
        }                                                                                \
    } } while (0)

__global__ __launch_bounds__(256, 2) void k_conv(
    const unsigned short* __restrict__ Dbf,
    const unsigned short* __restrict__ PB,
    unsigned short* __restrict__ outb,
    float* __restrict__ gsum, float* __restrict__ gsq)
{
    const int lane = threadIdx.x & 63;
    const int wave = threadIdx.x >> 6;
    const int bid = blockIdx.x;
    const int row_id = (bid & 7) * 256 + (bid >> 3);   // XCD-chunked, bijective (2048=8*256)
    const int g  = row_id & 127;
    int r2 = row_id >> 7;
    const int to = r2 & 7;
    const int b  = r2 >> 3;

    int yo0; bool has2;
    if (g < 64)       { yo0 = 4 * g;            has2 = true;  }
    else if (g < 127) { yo0 = 4 * (g - 64) + 1; has2 = true;  }
    else              { yo0 = 253;              has2 = false; }

    const int m = lane & 15, q = lane >> 4;

    __shared__ __align__(16) unsigned short shB[3 * 16 * 64 * 8];   // 48 KB
    __shared__ float shsum[64], shsq[64];
    if (threadIdx.x < 64) { shsum[threadIdx.x] = 0.f; shsq[threadIdx.x] = 0.f; }

    int ycy[2], yky[2], ny;
    if ((yo0 & 1) == 0) { ny = 1; ycy[0] = yo0 >> 1; yky[0] = 1; }
    else { ny = 2; ycy[0] = (yo0 + 1) >> 1; yky[0] = 0; ycy[1] = (yo0 - 1) >> 1; yky[1] = 2; }

    f32x4 acc0[4][4], acc1[4][4];   // [slot: a-even, a-odd, b-even, b-odd][nt]
    #pragma unroll
    for (int ch = 0; ch < 4; ++ch)
        #pragma unroll
        for (int nt = 0; nt < 4; ++nt) {
            acc0[ch][nt] = (f32x4){0.f, 0.f, 0.f, 0.f};
            acc1[ch][nt] = (f32x4){0.f, 0.f, 0.f, 0.f};
        }

    for (int kt = 0; kt < 3; ++kt) {
        int ct = to + 1 - kt;
        if (ct < 0 || ct >= TT) continue;        // uniform over block
        for (int iy = 0; iy < ny; ++iy) {        // uniform over block
            __syncthreads();                      // protect LDS from prior readers
            {
                const char* gsrc = (const char*)PB + (size_t)((kt * 3 + yky[iy]) * 3) * 16384;
                char* ldst = (char*)shB;
                #pragma unroll
                for (int r = 0; r < 12; ++r)
                    gld16(gsrc + r * 4096 + threadIdx.x * 16,
                          ldst + r * 4096 + wave * 1024);
            }
            // A0 (cxoff=0) for BOTH rows, pre-barrier: drained with staging.
            int cy0 = ycy[iy];
            int cy1 = has2 ? cy0 + 1 : cy0;                    // clamp for singleton
            size_t plane0 = ((size_t)((b * TT + ct) * YY + cy0)) * XX;
            size_t plane1 = ((size_t)((b * TT + ct) * YY + cy1)) * XX;
            FragU Aa0[4], Ab0[4], Aa1[4], Ab1[4];
            {
                const unsigned short* pa0 = Dbf + (plane0 + (size_t)(2 * wave * 16 + m)) * CINv;
                const unsigned short* pb0 = Dbf + (plane0 + (size_t)((2 * wave + 1) * 16 + m)) * CINv;
                const unsigned short* pa1 = Dbf + (plane1 + (size_t)(2 * wave * 16 + m)) * CINv;
                const unsigned short* pb1 = Dbf + (plane1 + (size_t)((2 * wave + 1) * 16 + m)) * CINv;
                #pragma unroll
                for (int kc = 0; kc < 4; ++kc) {
                    Aa0[kc].u = *(const u32x4*)(pa0 + kc * 32 + q * 8);
                    Ab0[kc].u = *(const u32x4*)(pb0 + kc * 32 + q * 8);
                    Aa1[kc].u = *(const u32x4*)(pa1 + kc * 32 + q * 8);
                    Ab1[kc].u = *(const u32x4*)(pb1 + kc * 32 + q * 8);
                }
            }
            __syncthreads();

            BPASS2(shB + 8192,  0);   // kx=1 -> even-parity outputs (A0)
            BPASS2(shB + 16384, 1);   // kx=2 -> odd-parity outputs  (A0)

            // A1 (cxoff=1) into the same registers (only the b-chunk can hit 128)
            {
                int cxb1 = (2 * wave + 1) * 16 + m + 1; if (cxb1 > 127) cxb1 = 127;
                const unsigned short* pa0 = Dbf + (plane0 + (size_t)(2 * wave * 16 + m + 1)) * CINv;
                const unsigned short* pb0 = Dbf + (plane0 + (size_t)cxb1) * CINv;
                const unsigned short* pa1 = Dbf + (plane1 + (size_t)(2 * wave * 16 + m + 1)) * CINv;
                const unsigned short* pb1 = Dbf + (plane1 + (size_t)cxb1) * CINv;
                #pragma unroll
                for (int kc = 0; kc < 4; ++kc) {
                    Aa0[kc].u = *(const u32x4*)(pa0 + kc * 32 + q * 8);
                    Ab0[kc].u = *(const u32x4*)(pb0 + kc * 32 + q * 8);
                    Aa1[kc].u = *(const u32x4*)(pa1 + kc * 32 + q * 8);
                    Ab1[kc].u = *(const u32x4*)(pb1 + kc * 32 + q * 8);
                }
            }
            BPASS2(shB + 0, 1);       // kx=0 -> odd-parity outputs (A1)
        }
    }

    // epilogue: bf16 store + per-channel partial stats (both rows)
    float sl[4] = {0.f,0.f,0.f,0.f}, sq[4] = {0.f,0.f,0.f,0.f};
    {
        size_t rowbase = ((size_t)((b * TT + to) * YOv + yo0)) * XOv;
        #pragma unroll
        for (int ch = 0; ch < 4; ++ch) {
            int cb8 = 2 * wave + (ch >> 1);
            int px = ch & 1;
            #pragma unroll
            for (int nt = 0; nt < 4; ++nt) {
                int c = nt * 16 + m;
                #pragma unroll
                for (int i = 0; i < 4; ++i) {
                    int r = q * 4 + i;
                    int xo = 2 * (cb8 * 16 + r) + px;
                    if (xo < XOv) {
                        float v = acc0[ch][nt][i];
                        outb[(rowbase + xo) * COUTv + c] = f2bf(v);
                        sl[nt] += v; sq[nt] += v * v;
                    }
                }
            }
        }
    }
    if (has2) {
        size_t rowbase = ((size_t)((b * TT + to) * YOv + (yo0 + 2))) * XOv;
        #pragma unroll
        for (int ch = 0; ch < 4; ++ch) {
            int cb8 = 2 * wave + (ch >> 1);
            int px = ch & 1;
            #pragma unroll
            for (int nt = 0; nt < 4; ++nt) {
                int c = nt * 16 + m;
                #pragma unroll
                for (int i = 0; i < 4; ++i) {
                    int r = q * 4 + i;
                    int xo = 2 * (cb8 * 16 + r) + px;
                    if (xo < XOv) {
                        float v = acc1[ch][nt][i];
                        outb[(rowbase + xo) * COUTv + c] = f2bf(v);
                        sl[nt] += v; sq[nt] += v * v;
                    }
                }
            }
        }
    }
    #pragma unroll
    for (int nt = 0; nt < 4; ++nt) {
        sl[nt] += __shfl_xor(sl[nt], 16); sl[nt] += __shfl_xor(sl[nt], 32);
        sq[nt] += __shfl_xor(sq[nt], 16); sq[nt] += __shfl_xor(sq[nt], 32);
    }
    if (lane < 16) {
        #pragma unroll
        for (int nt = 0; nt < 4; ++nt) {
            atomicAdd(&shsum[nt * 16 + lane], sl[nt]);
            atomicAdd(&shsq [nt * 16 + lane], sq[nt]);
        }
    }
    __syncthreads();
    if (threadIdx.x < 64) {
        unsafeAtomicAdd(&gsum[threadIdx.x], shsum[threadIdx.x]);
        unsafeAtomicAdd(&gsq [threadIdx.x], shsq [threadIdx.x]);
    }
}

// ---------------- pass 6: finalize BN stats ----------------
__global__ __launch_bounds__(64) void k_final(
    const float* __restrict__ gsum, const float* __restrict__ gsq,
    const unsigned int* __restrict__ ncnt,
    const float* __restrict__ gamma, const float* __restrict__ beta,
    float* __restrict__ scale, float* __restrict__ shift)
{
    int c = threadIdx.x;
    float nf = (float)max(*ncnt, 1u);
    float mean = gsum[c] / nf;
    float var  = gsq[c] / nf - mean * mean;
    float rstd = rsqrtf(var + 1e-5f);
    float sc = rstd * gamma[c];
    scale[c] = sc;
    shift[c] = beta[c] - mean * sc;
}

// ---------------- pass 7: normalize + mask + relu (bf16 -> fp32) ----------------
__global__ __launch_bounds__(256) void k_norm(
    const unsigned short* __restrict__ outb, float* __restrict__ out,
    const unsigned char* __restrict__ mask,
    const float* __restrict__ scale, const float* __restrict__ shift)
{
    __shared__ float ssc[64], ssh[64];
    if (threadIdx.x < 64) { ssc[threadIdx.x] = scale[threadIdx.x]; ssh[threadIdx.x] = shift[threadIdx.x]; }
    __syncthreads();
    size_t t = (size_t)blockIdx.x * 256 + threadIdx.x;
    size_t e = t * 8;
    if (e >= OUT_ELEMS) return;
    Pack8 p; p.u = *(const u32x4*)(outb + e);
    int c = (int)(e & 63);
    size_t site = e >> 6;
    float4 v0, v1;
    if (mask[site]) {
        float w[8];
        #pragma unroll
        for (int j = 0; j < 8; ++j) {
            float f = __uint_as_float((unsigned)p.s[j] << 16);
            w[j] = fmaxf(fmaf(f, ssc[c + j], ssh[c + j]), 0.f);
        }
        v0 = make_float4(w[0], w[1], w[2], w[3]);
        v1 = make_float4(w[4], w[5], w[6], w[7]);
    } else {
        v0 = make_float4(0.f, 0.f, 0.f, 0.f);
        v1 = v0;
    }
    *(float4*)(out + e) = v0;
    *(float4*)(out + e + 4) = v1;
}

// ---------------- launch ----------------
extern "C" void kernel_launch(void* const* d_in, const int* in_sizes, int n_in,
                              void* d_out, int out_size, void* d_ws, size_t ws_size,
                              hipStream_t stream)
{
    const float* feats = (const float*)d_in[0];
    const float* W     = (const float*)d_in[1];
    const float* gamma = (const float*)d_in[2];
    const float* beta  = (const float*)d_in[3];
    const int* cb = (const int*)d_in[4];
    const int* ct = (const int*)d_in[5];
    const int* cy = (const int*)d_in[6];
    const int* cx = (const int*)d_in[7];
    float* out = (float*)d_out;

    char* ws = (char*)d_ws;
    float*          gsum = (float*)(ws + OFF_STATS);
    float*          gsq  = gsum + 64;
    unsigned int*   ncnt = (unsigned int*)(ws + OFF_STATS + 512);
    unsigned int*   cnt  = (unsigned int*)(ws + OFF_CNT);
    unsigned short* Dbf  = (unsigned short*)(ws + OFF_DBF);
    unsigned short* PB   = (unsigned short*)(ws + OFF_PB);
    unsigned char*  mask = (unsigned char*)(ws + OFF_MASK);
    float*          scale= (float*)(ws + OFF_SS);
    float*          shift= scale + 64;
    int*            idx  = (int*)(ws + OFF_IDX);
    unsigned short* outb = (unsigned short*)(ws + OFF_OUTB);   // aliases idx (ordered)

    hipMemsetAsync(d_ws, 0, ZERO_BYTES, stream);

    k_count<<<NVOX / 256, 256, 0, stream>>>(cb, ct, cy, cx, cnt, idx);
    k_gather<<<NSITES * 16 / 256, 256, 0, stream>>>(feats, cnt, idx, Dbf);
    k_pack<<<27 * 16, 64, 0, stream>>>(W, PB);
    k_mask<<<(OUT_SITES + 255) / 256, 256, 0, stream>>>(cnt, mask, ncnt);
    k_conv<<<2048, 256, 0, stream>>>(Dbf, PB, outb, gsum, gsq);
    k_final<<<1, 64, 0, stream>>>(gsum, gsq, ncnt, gamma, beta, scale, shift);
    k_norm<<<(int)((OUT_ELEMS / 8 + 255) / 256), 256, 0, stream>>>(outb, out, mask, scale, shift);
}